// Round 1
// baseline (216.122 us; speedup 1.0000x reference)
//
#include <hip/hip_runtime.h>
#include <stdint.h>

typedef unsigned short u16;
typedef short bfrag __attribute__((ext_vector_type(8)));   // 8 bf16 (4 VGPR) MFMA A/B frag
typedef float ffrag __attribute__((ext_vector_type(4)));   // 4 f32 MFMA C/D frag
typedef u16 us4 __attribute__((ext_vector_type(4)));

#define HW 1024
#define C_DIM 512
#define O3 1536
#define BATCH 16

__device__ __forceinline__ u16 f2bf(float f) {
    uint32_t u = __builtin_bit_cast(uint32_t, f);
    u += 0x7FFFu + ((u >> 16) & 1u);           // RNE
    return (u16)(u >> 16);
}
__device__ __forceinline__ float bf2f(u16 v) {
    return __builtin_bit_cast(float, (uint32_t)v << 16);
}
__device__ __forceinline__ void async16(const u16* src, u16* ldsDst) {
    // direct global->LDS DMA, 16B/lane; LDS dest must be wave-uniform base (+lane*16 implicit)
    __builtin_amdgcn_global_load_lds(
        (const __attribute__((address_space(1))) uint32_t*)src,
        (__attribute__((address_space(3))) uint32_t*)ldsDst, 16, 0, 0);
}

// ---------------- f32 -> bf16 weight conversion ----------------
__global__ __launch_bounds__(256) void cvt_kernel(const float* __restrict__ src,
                                                  u16* __restrict__ dst, int n4) {
    int i = blockIdx.x * 256 + threadIdx.x;
    if (i < n4) {
        float4 v = ((const float4*)src)[i];
        us4 o = { f2bf(v.x), f2bf(v.y), f2bf(v.z), f2bf(v.w) };
        ((us4*)dst)[i] = o;
    }
}

// ---------------- GroupNorm: per (batch,group) block ----------------
// writes xg  [B][C][HW]  bf16  (residual / proj epilogue layout)
//        xgt [B][HW][C]  bf16  (QKV GEMM A-operand layout)
__global__ __launch_bounds__(256) void groupnorm_kernel(
    const float* __restrict__ x, const float* __restrict__ gw, const float* __restrict__ gb,
    u16* __restrict__ xg, u16* __restrict__ xgt)
{
    __shared__ u16 tile[16 * 1032];   // [ci][hw], padded stride vs bank conflicts
    __shared__ float red[8];
    const int tid = threadIdx.x;
    const int batch = blockIdx.x >> 5, g = blockIdx.x & 31;
    const float* xp = x + ((size_t)batch * C_DIM + g * 16) * HW;

    float s = 0.f, ss = 0.f;
#pragma unroll
    for (int it = 0; it < 16; ++it) {
        int i4 = it * 256 + tid;
        float4 v = ((const float4*)xp)[i4];
        int ci = i4 >> 8;
        int hw = (i4 & 255) * 4;
        s += v.x + v.y + v.z + v.w;
        ss += v.x * v.x + v.y * v.y + v.z * v.z + v.w * v.w;
        us4 u = { f2bf(v.x), f2bf(v.y), f2bf(v.z), f2bf(v.w) };
        *(us4*)&tile[ci * 1032 + hw] = u;
    }
#pragma unroll
    for (int m = 1; m <= 32; m <<= 1) { s += __shfl_xor(s, m, 64); ss += __shfl_xor(ss, m, 64); }
    if ((tid & 63) == 0) { red[tid >> 6] = s; red[4 + (tid >> 6)] = ss; }
    __syncthreads();
    float S = red[0] + red[1] + red[2] + red[3];
    float SS = red[4] + red[5] + red[6] + red[7];
    const float mean = S * (1.f / 16384.f);
    const float istd = rsqrtf(SS * (1.f / 16384.f) - mean * mean + 1e-5f);

    u16* xgp = xg + ((size_t)batch * C_DIM + g * 16) * HW;
#pragma unroll
    for (int it = 0; it < 16; ++it) {
        int i4 = it * 256 + tid;
        int ci = i4 >> 8;
        int hw = (i4 & 255) * 4;
        us4 u = *(us4*)&tile[ci * 1032 + hw];
        float sc = gw[g * 16 + ci] * istd;
        float bi = gb[g * 16 + ci] - mean * sc;
        us4 o = { f2bf(bf2f(u[0]) * sc + bi), f2bf(bf2f(u[1]) * sc + bi),
                  f2bf(bf2f(u[2]) * sc + bi), f2bf(bf2f(u[3]) * sc + bi) };
        *(us4*)&xgp[(size_t)ci * HW + hw] = o;
    }
    // transposed write: 4 channels per thread, contiguous 8B stores
    u16* xtp = xgt + (size_t)batch * HW * C_DIM + g * 16;
#pragma unroll
    for (int it = 0; it < 16; ++it) {
        int hw = (tid >> 2) + it * 64;
        int c0 = (tid & 3) * 4;
        us4 o;
#pragma unroll
        for (int k2 = 0; k2 < 4; ++k2) {
            int ci = c0 + k2;
            float sc = gw[g * 16 + ci] * istd;
            float bi = gb[g * 16 + ci] - mean * sc;
            o[k2] = f2bf(bf2f(tile[ci * 1032 + hw]) * sc + bi);
        }
        *(us4*)&xtp[(size_t)hw * C_DIM + c0] = o;
    }
}

// ---------------- GEMM: D[M][N] = A[M][512] * B[N][512]^T  (bf16 in, f32 acc) ----------
// 128x128 tile, BK=32, 4 waves (2x2 of 64x64), prefetch + 1 barrier per K-step.
// LDS chunk-swizzle: chunk' = chunk ^ (row&3)  (16B chunks, 4/row) — applied on the
// pre-swizzled global source at staging and on the ds_read address (rule #21).
// EPI=0: bf16 store (ldOut). EPI=1: f32 store + bias[row] + bf16 residual.
template<int EPI>
__global__ __launch_bounds__(256) void gemm_kernel(
    const u16* __restrict__ A, const u16* __restrict__ B, void* __restrict__ Out,
    const float* __restrict__ bias, const u16* __restrict__ resid,
    int Ntiles, int ldOut, long aBatch, long bBatch, long oBatch, long rBatch)
{
    __shared__ u16 As[2][128 * 32];
    __shared__ u16 Bs[2][128 * 32];
    const int tid = threadIdx.x;
    const int l = tid & 63, w = tid >> 6;
    const int batch = blockIdx.y;
    const int tm = blockIdx.x / Ntiles, tn = blockIdx.x % Ntiles;
    A += (size_t)batch * aBatch + (size_t)tm * 128 * 512;
    B += (size_t)batch * bBatch + (size_t)tn * 128 * 512;

    auto stage = [&](const u16* gbase, u16* lds, int kt) {
#pragma unroll
        for (int i = 0; i < 2; ++i) {
            int L = i * 256 + tid;
            int row = L >> 2, cs = L & 3;
            int c = cs ^ (row & 3);
            async16(gbase + (size_t)row * 512 + kt * 32 + c * 8,
                    lds + (size_t)(i * 256 + (tid & 192)) * 8);
        }
    };

    ffrag acc[4][4] = {};
    stage(A, As[0], 0); stage(B, Bs[0], 0);
    __syncthreads();
    const int wr = (w >> 1) * 64, wc = (w & 1) * 64;
    for (int kt = 0; kt < 16; ++kt) {
        const int cur = kt & 1;
        if (kt < 15) { stage(A, As[cur ^ 1], kt + 1); stage(B, Bs[cur ^ 1], kt + 1); }
        bfrag a[4], bb[4];
#pragma unroll
        for (int i = 0; i < 4; ++i) {
            int row = wr + i * 16 + (l & 15);
            int ch = (l >> 4) ^ (row & 3);
            a[i] = *(const bfrag*)&As[cur][row * 32 + ch * 8];
            int col = wc + i * 16 + (l & 15);
            int ch2 = (l >> 4) ^ (col & 3);
            bb[i] = *(const bfrag*)&Bs[cur][col * 32 + ch2 * 8];
        }
#pragma unroll
        for (int i = 0; i < 4; ++i)
#pragma unroll
            for (int j = 0; j < 4; ++j)
                acc[i][j] = __builtin_amdgcn_mfma_f32_16x16x32_bf16(a[i], bb[j], acc[i][j], 0, 0, 0);
        __syncthreads();
    }
    // epilogue: D row = (l>>4)*4+reg, col = l&15 (m89-verified layout)
    const int rbase = tm * 128 + wr + ((l >> 4) << 2);
    const int cbase = tn * 128 + wc + (l & 15);
    if (EPI == 0) {
        u16* outp = (u16*)Out + (size_t)batch * oBatch;
#pragma unroll
        for (int i = 0; i < 4; ++i)
#pragma unroll
            for (int j = 0; j < 4; ++j)
#pragma unroll
                for (int r = 0; r < 4; ++r)
                    outp[(size_t)(rbase + i * 16 + r) * ldOut + cbase + j * 16] = f2bf(acc[i][j][r]);
    } else {
        float* outp = (float*)Out + (size_t)batch * oBatch;
        const u16* rp = resid + (size_t)batch * rBatch;
#pragma unroll
        for (int i = 0; i < 4; ++i)
#pragma unroll
            for (int j = 0; j < 4; ++j)
#pragma unroll
                for (int r = 0; r < 4; ++r) {
                    int rr = rbase + i * 16 + r, cc = cbase + j * 16;
                    outp[(size_t)rr * ldOut + cc] =
                        acc[i][j][r] + bias[rr] + bf2f(rp[(size_t)rr * ldOut + cc]);
                }
    }
}

// ---------------- V transpose: qkv_t[b][m][1024+h*64+d] -> v_t[(b,h)][d][m] ----------------
__global__ __launch_bounds__(256) void vtrans_kernel(const u16* __restrict__ qkvt,
                                                     u16* __restrict__ vt)
{
    __shared__ u16 t[64][65];
    const int bid = blockIdx.x;
    const int mt = bid & 15, h = (bid >> 4) & 7, batch = bid >> 7;
    const u16* src = qkvt + (size_t)batch * HW * O3 + (size_t)mt * 64 * O3 + 1024 + h * 64;
    u16* dst = vt + ((size_t)(batch * 8 + h) * 64) * HW + mt * 64;
    const int tid = threadIdx.x;
#pragma unroll
    for (int i = 0; i < 4; ++i) {
        int m = (tid >> 4) + i * 16;
        int d0 = (tid & 15) * 4;
        us4 v = *(const us4*)&src[(size_t)m * O3 + d0];
        t[m][d0] = v[0]; t[m][d0 + 1] = v[1]; t[m][d0 + 2] = v[2]; t[m][d0 + 3] = v[3];
    }
    __syncthreads();
#pragma unroll
    for (int i = 0; i < 4; ++i) {
        int d = (tid >> 4) + i * 16;
        int m0 = (tid & 15) * 4;
        us4 v = { t[m0][d], t[m0 + 1][d], t[m0 + 2][d], t[m0 + 3][d] };
        *(us4*)&dst[(size_t)d * HW + m0] = v;
    }
}

// ---------------- Flash attention: block = (b,h, 128-row n-tile), 4 waves x 32 rows ----------
__global__ __launch_bounds__(256) void attn_kernel(const u16* __restrict__ qkvt,
                                                   const u16* __restrict__ vt,
                                                   u16* __restrict__ ht)
{
    __shared__ u16 Ks[2][64 * 64];   // [m][d], chunk-swizzled
    __shared__ u16 Vs[2][64 * 64];   // [d][m], chunk-swizzled
    __shared__ u16 Ps[4][32 * 64];   // per-wave P tile [n][m], chunk-swizzled
    const int tid = threadIdx.x, l = tid & 63, w = tid >> 6;
    const int bid = blockIdx.x;
    const int nt = bid & 7, h = (bid >> 3) & 7, batch = bid >> 6;
    const u16* Qb = qkvt + (size_t)batch * HW * O3 + h * 64;
    const u16* Kb = Qb + 512;
    const u16* Vtb = vt + (size_t)(batch * 8 + h) * 64 * HW;
    const int n0 = nt * 128 + w * 32;

    bfrag qf[2][2];
#pragma unroll
    for (int i = 0; i < 2; ++i)
#pragma unroll
        for (int kc = 0; kc < 2; ++kc)
            qf[i][kc] = *(const bfrag*)&Qb[(size_t)(n0 + i * 16 + (l & 15)) * O3 + kc * 32 + (l >> 4) * 8];

    auto stageK = [&](int ms, u16* lds) {
#pragma unroll
        for (int i = 0; i < 2; ++i) {
            int L = i * 256 + tid;
            int row = L >> 3, cs = L & 7, c = cs ^ (row & 7);
            async16(&Kb[(size_t)(ms * 64 + row) * O3 + c * 8],
                    lds + (size_t)(i * 256 + (tid & 192)) * 8);
        }
    };
    auto stageV = [&](int ms, u16* lds) {
#pragma unroll
        for (int i = 0; i < 2; ++i) {
            int L = i * 256 + tid;
            int row = L >> 3, cs = L & 7, c = cs ^ (row & 7);
            async16(&Vtb[(size_t)row * HW + ms * 64 + c * 8],
                    lds + (size_t)(i * 256 + (tid & 192)) * 8);
        }
    };

    ffrag hacc[2][4] = {};
    float mrun[2][4], lrun[2][4];
#pragma unroll
    for (int ni = 0; ni < 2; ++ni)
#pragma unroll
        for (int r = 0; r < 4; ++r) { mrun[ni][r] = -1e30f; lrun[ni][r] = 0.f; }

    stageK(0, Ks[0]); stageV(0, Vs[0]);
    __syncthreads();

    for (int ms = 0; ms < 16; ++ms) {
        const int cur = ms & 1;
        if (ms < 15) { stageK(ms + 1, Ks[cur ^ 1]); stageV(ms + 1, Vs[cur ^ 1]); }
        // S = Q K^T  (row n from Q-frag, col m from K-frag)
        ffrag s[2][4] = {};
#pragma unroll
        for (int mj = 0; mj < 4; ++mj)
#pragma unroll
            for (int kc = 0; kc < 2; ++kc) {
                int row = mj * 16 + (l & 15);
                int ch = (kc * 4 + (l >> 4)) ^ (row & 7);
                bfrag kf = *(const bfrag*)&Ks[cur][row * 64 + ch * 8];
#pragma unroll
                for (int ni = 0; ni < 2; ++ni)
                    s[ni][mj] = __builtin_amdgcn_mfma_f32_16x16x32_bf16(qf[ni][kc], kf, s[ni][mj], 0, 0, 0);
            }
        // online softmax: rows = (l>>4)*4+r (+16*ni), cols spread over l&15 and mj
        float corr[2][4];
#pragma unroll
        for (int ni = 0; ni < 2; ++ni)
#pragma unroll
            for (int r = 0; r < 4; ++r) {
                float mx = fmaxf(fmaxf(s[ni][0][r], s[ni][1][r]), fmaxf(s[ni][2][r], s[ni][3][r]));
#pragma unroll
                for (int m = 1; m <= 8; m <<= 1) mx = fmaxf(mx, __shfl_xor(mx, m, 64));
                mx *= 0.125f;
                float mnew = fmaxf(mrun[ni][r], mx);
                corr[ni][r] = __expf(mrun[ni][r] - mnew);
                mrun[ni][r] = mnew;
            }
#pragma unroll
        for (int ni = 0; ni < 2; ++ni) {
            float ps[4] = {0.f, 0.f, 0.f, 0.f};
#pragma unroll
            for (int mj = 0; mj < 4; ++mj)
#pragma unroll
                for (int r = 0; r < 4; ++r) {
                    float p = __expf(s[ni][mj][r] * 0.125f - mrun[ni][r]);
                    ps[r] += p;
                    int nl = ni * 16 + (l >> 4) * 4 + r;
                    int m = mj * 16 + (l & 15);
                    int ch = (m >> 3) ^ (nl & 7);
                    Ps[w][nl * 64 + ch * 8 + (m & 7)] = f2bf(p);
                }
#pragma unroll
            for (int r = 0; r < 4; ++r) {
                float t = ps[r];
#pragma unroll
                for (int m = 1; m <= 8; m <<= 1) t += __shfl_xor(t, m, 64);
                lrun[ni][r] = lrun[ni][r] * corr[ni][r] + t;
#pragma unroll
                for (int dj = 0; dj < 4; ++dj) hacc[ni][dj][r] *= corr[ni][r];
            }
        }
        // H += P V   (A-frag rows n from Ps, B-frag cols d from Vs)
#pragma unroll
        for (int kc = 0; kc < 2; ++kc) {
            bfrag pf[2];
#pragma unroll
            for (int ni = 0; ni < 2; ++ni) {
                int row = ni * 16 + (l & 15);
                int ch = (kc * 4 + (l >> 4)) ^ (row & 7);
                pf[ni] = *(const bfrag*)&Ps[w][row * 64 + ch * 8];
            }
#pragma unroll
            for (int dj = 0; dj < 4; ++dj) {
                int row = dj * 16 + (l & 15);
                int ch = (kc * 4 + (l >> 4)) ^ (row & 7);
                bfrag vf = *(const bfrag*)&Vs[cur][row * 64 + ch * 8];
#pragma unroll
                for (int ni = 0; ni < 2; ++ni)
                    hacc[ni][dj] = __builtin_amdgcn_mfma_f32_16x16x32_bf16(pf[ni], vf, hacc[ni][dj], 0, 0, 0);
            }
        }
        __syncthreads();
    }
    // epilogue: h_t[b][n][h*64+d]
    u16* hp = ht + (size_t)batch * HW * C_DIM + h * 64;
#pragma unroll
    for (int ni = 0; ni < 2; ++ni)
#pragma unroll
        for (int dj = 0; dj < 4; ++dj)
#pragma unroll
            for (int r = 0; r < 4; ++r) {
                int n = n0 + ni * 16 + ((l >> 4) << 2) + r;
                int d = dj * 16 + (l & 15);
                hp[(size_t)n * C_DIM + d] = f2bf(hacc[ni][dj][r] / lrun[ni][r]);
            }
}

extern "C" void kernel_launch(void* const* d_in, const int* in_sizes, int n_in,
                              void* d_out, int out_size, void* d_ws, size_t ws_size,
                              hipStream_t stream)
{
    const float* x = (const float*)d_in[0];
    const float* gw = (const float*)d_in[1];
    const float* gb = (const float*)d_in[2];
    const float* qkvw = (const float*)d_in[3];
    const float* projw = (const float*)d_in[4];
    const float* projb = (const float*)d_in[5];
    float* out = (float*)d_out;
    char* ws = (char*)d_ws;
    // workspace map (bytes):
    u16* xg    = (u16*)(ws);               // 16.78 MB  [B][C][HW] bf16 (normed x)
    u16* xgt   = (u16*)(ws + 16777216);    // 16.78 MB  [B][HW][C]
    u16* qkvt  = (u16*)(ws + 33554432);    // 50.33 MB  [B][HW][1536]
    u16* vt    = (u16*)(ws + 83886080);    // 16.78 MB  [B*8][64][1024]
    u16* qkvwb = (u16*)(ws + 100663296);   // 1.57 MB
    u16* projwb= (u16*)(ws + 102236160);   // 0.52 MB   (total 102.76 MB)
    u16* ht    = xgt;                      // alias: xgt dead after QKV GEMM

    cvt_kernel<<<768, 256, 0, stream>>>(qkvw, qkvwb, 196608);
    cvt_kernel<<<256, 256, 0, stream>>>(projw, projwb, 65536);
    groupnorm_kernel<<<512, 256, 0, stream>>>(x, gw, gb, xg, xgt);
    // qkv_t[b][hw][o] = sum_c xgt[b][hw][c] * qkv_w[o][c]   (M=1024,N=1536,K=512)
    gemm_kernel<0><<<dim3(96, 16), 256, 0, stream>>>(
        xgt, qkvwb, qkvt, nullptr, nullptr, 12, 1536, 524288L, 0L, 1572864L, 0L);
    vtrans_kernel<<<2048, 256, 0, stream>>>(qkvt, vt);
    attn_kernel<<<1024, 256, 0, stream>>>(qkvt, vt, ht);
    // out[b][o][hw] = sum_c proj_w[o][c] * ht[b][hw][c] + proj_b[o] + xg[b][o][hw]
    gemm_kernel<1><<<dim3(32, 16), 256, 0, stream>>>(
        projwb, ht, out, projb, xg, 8, 1024, 0L, 524288L, 524288L, 524288L);
}

// Round 2
// 170.476 us; speedup vs baseline: 1.2678x; 1.2678x over previous
//
#include <hip/hip_runtime.h>
#include <stdint.h>

typedef unsigned short u16;
typedef short bfrag __attribute__((ext_vector_type(8)));   // 8 bf16 (4 VGPR) MFMA A/B frag
typedef float ffrag __attribute__((ext_vector_type(4)));   // 4 f32 MFMA C/D frag
typedef u16 us4 __attribute__((ext_vector_type(4)));

#define HW 1024
#define C_DIM 512
#define O3 1536
#define BATCH 16

__device__ __forceinline__ u16 f2bf(float f) {
    uint32_t u = __builtin_bit_cast(uint32_t, f);
    u += 0x7FFFu + ((u >> 16) & 1u);           // RNE
    return (u16)(u >> 16);
}
__device__ __forceinline__ float bf2f(u16 v) {
    return __builtin_bit_cast(float, (uint32_t)v << 16);
}
__device__ __forceinline__ void async16(const u16* src, u16* ldsDst) {
    // direct global->LDS DMA, 16B/lane; LDS dest is wave-uniform base (+lane*16 implicit)
    __builtin_amdgcn_global_load_lds(
        (const __attribute__((address_space(1))) uint32_t*)src,
        (__attribute__((address_space(3))) uint32_t*)ldsDst, 16, 0, 0);
}

// ---------------- f32 -> bf16 weight conversion ----------------
__global__ __launch_bounds__(256) void cvt_kernel(const float* __restrict__ src,
                                                  u16* __restrict__ dst, int n4) {
    int i = blockIdx.x * 256 + threadIdx.x;
    if (i < n4) {
        float4 v = ((const float4*)src)[i];
        us4 o = { f2bf(v.x), f2bf(v.y), f2bf(v.z), f2bf(v.w) };
        ((us4*)dst)[i] = o;
    }
}

// ---------------- GroupNorm: per (batch,group) block ----------------
__global__ __launch_bounds__(256) void groupnorm_kernel(
    const float* __restrict__ x, const float* __restrict__ gw, const float* __restrict__ gb,
    u16* __restrict__ xg, u16* __restrict__ xgt)
{
    __shared__ u16 tile[16 * 1032];   // [ci][hw], padded stride vs bank conflicts
    __shared__ float red[8];
    const int tid = threadIdx.x;
    const int batch = blockIdx.x >> 5, g = blockIdx.x & 31;
    const float* xp = x + ((size_t)batch * C_DIM + g * 16) * HW;

    float s = 0.f, ss = 0.f;
#pragma unroll
    for (int it = 0; it < 16; ++it) {
        int i4 = it * 256 + tid;
        float4 v = ((const float4*)xp)[i4];
        int ci = i4 >> 8;
        int hw = (i4 & 255) * 4;
        s += v.x + v.y + v.z + v.w;
        ss += v.x * v.x + v.y * v.y + v.z * v.z + v.w * v.w;
        us4 u = { f2bf(v.x), f2bf(v.y), f2bf(v.z), f2bf(v.w) };
        *(us4*)&tile[ci * 1032 + hw] = u;
    }
#pragma unroll
    for (int m = 1; m <= 32; m <<= 1) { s += __shfl_xor(s, m, 64); ss += __shfl_xor(ss, m, 64); }
    if ((tid & 63) == 0) { red[tid >> 6] = s; red[4 + (tid >> 6)] = ss; }
    __syncthreads();
    float S = red[0] + red[1] + red[2] + red[3];
    float SS = red[4] + red[5] + red[6] + red[7];
    const float mean = S * (1.f / 16384.f);
    const float istd = rsqrtf(SS * (1.f / 16384.f) - mean * mean + 1e-5f);

    u16* xgp = xg + ((size_t)batch * C_DIM + g * 16) * HW;
#pragma unroll
    for (int it = 0; it < 16; ++it) {
        int i4 = it * 256 + tid;
        int ci = i4 >> 8;
        int hw = (i4 & 255) * 4;
        us4 u = *(us4*)&tile[ci * 1032 + hw];
        float sc = gw[g * 16 + ci] * istd;
        float bi = gb[g * 16 + ci] - mean * sc;
        us4 o = { f2bf(bf2f(u[0]) * sc + bi), f2bf(bf2f(u[1]) * sc + bi),
                  f2bf(bf2f(u[2]) * sc + bi), f2bf(bf2f(u[3]) * sc + bi) };
        *(us4*)&xgp[(size_t)ci * HW + hw] = o;
    }
    u16* xtp = xgt + (size_t)batch * HW * C_DIM + g * 16;
#pragma unroll
    for (int it = 0; it < 16; ++it) {
        int hw = (tid >> 2) + it * 64;
        int c0 = (tid & 3) * 4;
        us4 o;
#pragma unroll
        for (int k2 = 0; k2 < 4; ++k2) {
            int ci = c0 + k2;
            float sc = gw[g * 16 + ci] * istd;
            float bi = gb[g * 16 + ci] - mean * sc;
            o[k2] = f2bf(bf2f(tile[ci * 1032 + hw]) * sc + bi);
        }
        *(us4*)&xtp[(size_t)hw * C_DIM + c0] = o;
    }
}

// ---------------- GEMM: D[M][N] = A[M][512] * B[N][512]^T  (bf16 in, f32 acc) ----------
template<int EPI>
__global__ __launch_bounds__(256) void gemm_kernel(
    const u16* __restrict__ A, const u16* __restrict__ B, void* __restrict__ Out,
    const float* __restrict__ bias, const u16* __restrict__ resid,
    int Ntiles, int ldOut, long aBatch, long bBatch, long oBatch, long rBatch)
{
    __shared__ u16 As[2][128 * 32];
    __shared__ u16 Bs[2][128 * 32];
    const int tid = threadIdx.x;
    const int l = tid & 63, w = tid >> 6;
    const int batch = blockIdx.y;
    const int tm = blockIdx.x / Ntiles, tn = blockIdx.x % Ntiles;
    A += (size_t)batch * aBatch + (size_t)tm * 128 * 512;
    B += (size_t)batch * bBatch + (size_t)tn * 128 * 512;

    auto stage = [&](const u16* gbase, u16* lds, int kt) {
#pragma unroll
        for (int i = 0; i < 2; ++i) {
            int L = i * 256 + tid;
            int row = L >> 2, cs = L & 3;
            int c = cs ^ (row & 3);
            async16(gbase + (size_t)row * 512 + kt * 32 + c * 8,
                    lds + (size_t)(i * 256 + (tid & 192)) * 8);
        }
    };

    ffrag acc[4][4] = {};
    stage(A, As[0], 0); stage(B, Bs[0], 0);
    __syncthreads();
    const int wr = (w >> 1) * 64, wc = (w & 1) * 64;
    for (int kt = 0; kt < 16; ++kt) {
        const int cur = kt & 1;
        if (kt < 15) { stage(A, As[cur ^ 1], kt + 1); stage(B, Bs[cur ^ 1], kt + 1); }
        bfrag a[4], bb[4];
#pragma unroll
        for (int i = 0; i < 4; ++i) {
            int row = wr + i * 16 + (l & 15);
            int ch = (l >> 4) ^ (row & 3);
            a[i] = *(const bfrag*)&As[cur][row * 32 + ch * 8];
            int col = wc + i * 16 + (l & 15);
            int ch2 = (l >> 4) ^ (col & 3);
            bb[i] = *(const bfrag*)&Bs[cur][col * 32 + ch2 * 8];
        }
#pragma unroll
        for (int i = 0; i < 4; ++i)
#pragma unroll
            for (int j = 0; j < 4; ++j)
                acc[i][j] = __builtin_amdgcn_mfma_f32_16x16x32_bf16(a[i], bb[j], acc[i][j], 0, 0, 0);
        __syncthreads();
    }
    const int rbase = tm * 128 + wr + ((l >> 4) << 2);
    const int cbase = tn * 128 + wc + (l & 15);
    if (EPI == 0) {
        u16* outp = (u16*)Out + (size_t)batch * oBatch;
#pragma unroll
        for (int i = 0; i < 4; ++i)
#pragma unroll
            for (int j = 0; j < 4; ++j)
#pragma unroll
                for (int r = 0; r < 4; ++r)
                    outp[(size_t)(rbase + i * 16 + r) * ldOut + cbase + j * 16] = f2bf(acc[i][j][r]);
    } else {
        float* outp = (float*)Out + (size_t)batch * oBatch;
        const u16* rp = resid + (size_t)batch * rBatch;
#pragma unroll
        for (int i = 0; i < 4; ++i)
#pragma unroll
            for (int j = 0; j < 4; ++j)
#pragma unroll
                for (int r = 0; r < 4; ++r) {
                    int rr = rbase + i * 16 + r, cc = cbase + j * 16;
                    outp[(size_t)rr * ldOut + cc] =
                        acc[i][j][r] + bias[rr] + bf2f(rp[(size_t)rr * ldOut + cc]);
                }
    }
}

// ---------------- V transpose: qkv_t[b][m][1024+h*64+d] -> v_t[(b,h)][d][m] ----------------
__global__ __launch_bounds__(256) void vtrans_kernel(const u16* __restrict__ qkvt,
                                                     u16* __restrict__ vt)
{
    __shared__ u16 t[64][65];
    const int bid = blockIdx.x;
    const int mt = bid & 15, h = (bid >> 4) & 7, batch = bid >> 7;
    const u16* src = qkvt + (size_t)batch * HW * O3 + (size_t)mt * 64 * O3 + 1024 + h * 64;
    u16* dst = vt + ((size_t)(batch * 8 + h) * 64) * HW + mt * 64;
    const int tid = threadIdx.x;
#pragma unroll
    for (int i = 0; i < 4; ++i) {
        int m = (tid >> 4) + i * 16;
        int d0 = (tid & 15) * 4;
        us4 v = *(const us4*)&src[(size_t)m * O3 + d0];
        t[m][d0] = v[0]; t[m][d0 + 1] = v[1]; t[m][d0 + 2] = v[2]; t[m][d0 + 3] = v[3];
    }
    __syncthreads();
#pragma unroll
    for (int i = 0; i < 4; ++i) {
        int d = (tid >> 4) + i * 16;
        int m0 = (tid & 15) * 4;
        us4 v = { t[m0][d], t[m0 + 1][d], t[m0 + 2][d], t[m0 + 3][d] };
        *(us4*)&dst[(size_t)d * HW + m0] = v;
    }
}

// ---------------- Flash attention, swapped-QK^T (S^T = K·Q^T) ----------------
// 8 waves x 32 rows = 256 q-rows/block; grid = 16b*8h*4nt = 512 = 2 blocks/CU exactly.
// Per lane after mfma(K,Q): S^T[m = mj*16+4g+r][n = ni*16+(l&15)], g=l>>4.
// Softmax axis (m) is register-direction: 15-op tree + 2 shfl_xor; P packed 4-wide
// into per-wave Ps[n][m] (16B-chunk XOR swizzle) for the PV A-fragment.
__global__ __launch_bounds__(512, 4) void attn_kernel(const u16* __restrict__ qkvt,
                                                      const u16* __restrict__ vt,
                                                      u16* __restrict__ ht)
{
    __shared__ u16 Ks[2][64 * 64];   // [m][d], 16B-chunk swizzled
    __shared__ u16 Vs[2][64 * 64];   // [d][m], 16B-chunk swizzled
    __shared__ u16 Ps[8][32 * 64];   // per-wave P [n][m], 16B-chunk swizzled
    const int tid = threadIdx.x, l = tid & 63, w = tid >> 6, g = l >> 4;
    const int bid = blockIdx.x;
    const int nt = bid & 3, h = (bid >> 2) & 7, batch = bid >> 5;
    const u16* Qb = qkvt + (size_t)batch * HW * O3 + h * 64;
    const u16* Kb = Qb + 512;
    const u16* Vtb = vt + (size_t)(batch * 8 + h) * 64 * HW;
    const int n0 = nt * 256 + w * 32;
    const float cexp = 0.125f * 1.44269504f;   // softmax scale * log2(e)

    bfrag qf[2][2];
#pragma unroll
    for (int ni = 0; ni < 2; ++ni)
#pragma unroll
        for (int kc = 0; kc < 2; ++kc)
            qf[ni][kc] = *(const bfrag*)&Qb[(size_t)(n0 + ni * 16 + (l & 15)) * O3 + kc * 32 + g * 8];

    // 512 threads stage one full 64x64 bf16 tile (8KB) per call
    auto stageK = [&](int ms, u16* lds) {
        int row = tid >> 3, c = (tid & 7) ^ (row & 7);
        async16(&Kb[(size_t)(ms * 64 + row) * O3 + c * 8], lds + (size_t)(tid & 448) * 8);
    };
    auto stageV = [&](int ms, u16* lds) {
        int row = tid >> 3, c = (tid & 7) ^ (row & 7);
        async16(&Vtb[(size_t)row * HW + ms * 64 + c * 8], lds + (size_t)(tid & 448) * 8);
    };

    ffrag hacc[2][4] = {};
    float M[2] = { -1e30f, -1e30f }, L[2] = { 0.f, 0.f };

    stageK(0, Ks[0]); stageV(0, Vs[0]);
    __syncthreads();

    for (int ms = 0; ms < 16; ++ms) {
        const int cur = ms & 1;
        if (ms < 15) { stageK(ms + 1, Ks[cur ^ 1]); stageV(ms + 1, Vs[cur ^ 1]); }

        // S^T = K Q^T : A-frag = K rows (m), B-frag = Q cols (n)
        ffrag s[2][4] = {};
#pragma unroll
        for (int mj = 0; mj < 4; ++mj)
#pragma unroll
            for (int kc = 0; kc < 2; ++kc) {
                int m = mj * 16 + (l & 15);
                int ch = (kc * 4 + g) ^ (m & 7);
                bfrag kf = *(const bfrag*)&Ks[cur][m * 64 + ch * 8];
#pragma unroll
                for (int ni = 0; ni < 2; ++ni)
                    s[ni][mj] = __builtin_amdgcn_mfma_f32_16x16x32_bf16(kf, qf[ni][kc], s[ni][mj], 0, 0, 0);
            }

#pragma unroll
        for (int ni = 0; ni < 2; ++ni) {
            // row max over this lane's 16 m-values, then combine the 4 g-groups
            float pm = fmaxf(fmaxf(fmaxf(s[ni][0][0], s[ni][0][1]), fmaxf(s[ni][0][2], s[ni][0][3])),
                             fmaxf(fmaxf(s[ni][1][0], s[ni][1][1]), fmaxf(s[ni][1][2], s[ni][1][3])));
            float pm2 = fmaxf(fmaxf(fmaxf(s[ni][2][0], s[ni][2][1]), fmaxf(s[ni][2][2], s[ni][2][3])),
                              fmaxf(fmaxf(s[ni][3][0], s[ni][3][1]), fmaxf(s[ni][3][2], s[ni][3][3])));
            pm = fmaxf(pm, pm2);
            pm = fmaxf(pm, __shfl_xor(pm, 16, 64));
            pm = fmaxf(pm, __shfl_xor(pm, 32, 64));
            float mnew = fmaxf(M[ni], pm * cexp);
            if (!__all(mnew - M[ni] <= 4.0f)) {      // defer-max: skip rescale when growth small
                float corr = exp2f(M[ni] - mnew);
                M[ni] = mnew;
                L[ni] *= corr;
#pragma unroll
                for (int r = 0; r < 4; ++r) {
                    float cb = __shfl(corr, g * 4 + r, 64);  // corr for hacc row 4g+r
#pragma unroll
                    for (int dj = 0; dj < 4; ++dj) hacc[ni][dj][r] *= cb;
                }
            }
            float rs = 0.f;
            const int nl = ni * 16 + (l & 15);
#pragma unroll
            for (int mj = 0; mj < 4; ++mj) {
                us4 pk;
#pragma unroll
                for (int r = 0; r < 4; ++r) {
                    float p = exp2f(fmaf(s[ni][mj][r], cexp, -M[ni]));
                    rs += p;
                    pk[r] = f2bf(p);
                }
                int c16 = (mj * 2 + (g >> 1)) ^ (nl & 7);
                *(us4*)((char*)&Ps[w][0] + nl * 128 + c16 * 16 + (g & 1) * 8) = pk;
            }
            rs += __shfl_xor(rs, 16, 64);
            rs += __shfl_xor(rs, 32, 64);
            L[ni] += rs;
        }

        // H += P V : A-frag = P rows (n) from Ps, B-frag = V cols (d) from Vs
#pragma unroll
        for (int kc = 0; kc < 2; ++kc) {
            bfrag pf[2];
#pragma unroll
            for (int ni = 0; ni < 2; ++ni) {
                int nl = ni * 16 + (l & 15);
                int c16 = (kc * 4 + g) ^ (nl & 7);
                pf[ni] = *(const bfrag*)((char*)&Ps[w][0] + nl * 128 + c16 * 16);
            }
#pragma unroll
            for (int dj = 0; dj < 4; ++dj) {
                int d = dj * 16 + (l & 15);
                int ch = (kc * 4 + g) ^ (d & 7);
                bfrag vf = *(const bfrag*)&Vs[cur][d * 64 + ch * 8];
#pragma unroll
                for (int ni = 0; ni < 2; ++ni)
                    hacc[ni][dj] = __builtin_amdgcn_mfma_f32_16x16x32_bf16(pf[ni], vf, hacc[ni][dj], 0, 0, 0);
            }
        }
        __syncthreads();
    }

    // epilogue: h_t[b][n][h*64+d]; hacc row n = n0+ni*16+4g+r, col d = dj*16+(l&15)
    u16* hp = ht + (size_t)batch * HW * C_DIM + h * 64;
#pragma unroll
    for (int ni = 0; ni < 2; ++ni) {
        float linv[4];
#pragma unroll
        for (int r = 0; r < 4; ++r) linv[r] = 1.0f / __shfl(L[ni], g * 4 + r, 64);
#pragma unroll
        for (int dj = 0; dj < 4; ++dj)
#pragma unroll
            for (int r = 0; r < 4; ++r) {
                int n = n0 + ni * 16 + g * 4 + r;
                int d = dj * 16 + (l & 15);
                hp[(size_t)n * C_DIM + d] = f2bf(hacc[ni][dj][r] * linv[r]);
            }
    }
}

extern "C" void kernel_launch(void* const* d_in, const int* in_sizes, int n_in,
                              void* d_out, int out_size, void* d_ws, size_t ws_size,
                              hipStream_t stream)
{
    const float* x = (const float*)d_in[0];
    const float* gw = (const float*)d_in[1];
    const float* gb = (const float*)d_in[2];
    const float* qkvw = (const float*)d_in[3];
    const float* projw = (const float*)d_in[4];
    const float* projb = (const float*)d_in[5];
    float* out = (float*)d_out;
    char* ws = (char*)d_ws;
    u16* xg    = (u16*)(ws);               // 16.78 MB  [B][C][HW] bf16 (normed x)
    u16* xgt   = (u16*)(ws + 16777216);    // 16.78 MB  [B][HW][C]
    u16* qkvt  = (u16*)(ws + 33554432);    // 50.33 MB  [B][HW][1536]
    u16* vt    = (u16*)(ws + 83886080);    // 16.78 MB  [B*8][64][1024]
    u16* qkvwb = (u16*)(ws + 100663296);   // 1.57 MB
    u16* projwb= (u16*)(ws + 102236160);   // 0.52 MB
    u16* ht    = xgt;                      // alias: xgt dead after QKV GEMM

    cvt_kernel<<<768, 256, 0, stream>>>(qkvw, qkvwb, 196608);
    cvt_kernel<<<256, 256, 0, stream>>>(projw, projwb, 65536);
    groupnorm_kernel<<<512, 256, 0, stream>>>(x, gw, gb, xg, xgt);
    gemm_kernel<0><<<dim3(96, 16), 256, 0, stream>>>(
        xgt, qkvwb, qkvt, nullptr, nullptr, 12, 1536, 524288L, 0L, 1572864L, 0L);
    vtrans_kernel<<<2048, 256, 0, stream>>>(qkvt, vt);
    attn_kernel<<<512, 512, 0, stream>>>(qkvt, vt, ht);
    gemm_kernel<1><<<dim3(32, 16), 256, 0, stream>>>(
        projwb, ht, out, projb, xg, 8, 1024, 0L, 524288L, 524288L, 524288L);
}